// Round 2
// baseline (49902.377 us; speedup 1.0000x reference)
//
#include <hip/hip_runtime.h>

#define T_STEPS 256
#define HH      100
#define KQ      32      // padded float4 chunks of h (H_pad = 128)
#define G4      400     // 4*H gate rows
#define ROWS    8       // batch rows per block
#define PMAT    51200   // 32 kq * 400 j * 4 kk floats per packed matrix

// ws float layout:
//   [0      .. 51200)   P1 = W_hh1 packed: P[kq][j][kk] = W[j][4*kq+kk] (0 if col>=100)
//   [51200  ..102400)   P2 = W_ih2 packed
//   [102400 ..153600)   P3 = W_hh2 packed
//   [153600 ..154000)   bias1 = b_ih1 + b_hh1
//   [154000 ..154400)   bias2 = b_ih2 + b_hh2
//   [154400 ..154800)   wi1   = W_ih1[:,0]
//   [154800 ..154900)   wlin  = W_lin[0][:]
//   [154900]            blin
#define WS_TOTAL 154901

__global__ __launch_bounds__(1024) void pack_kernel(
    const float* __restrict__ Whh1, const float* __restrict__ Wih2,
    const float* __restrict__ Whh2,
    const float* __restrict__ bih1, const float* __restrict__ bhh1,
    const float* __restrict__ bih2, const float* __restrict__ bhh2,
    const float* __restrict__ Wih1, const float* __restrict__ Wlin,
    const float* __restrict__ blin, float* __restrict__ ws) {
  int idx = blockIdx.x * 1024 + threadIdx.x;
  if (idx < 3 * PMAT) {
    int m   = idx / PMAT;
    int rem = idx - m * PMAT;          // (kq*400 + j)*4 + kk
    int kk  = rem & 3;
    int t2  = rem >> 2;
    int kq  = t2 / 400;
    int j   = t2 - kq * 400;
    int c   = kq * 4 + kk;
    const float* W = (m == 0) ? Whh1 : (m == 1) ? Wih2 : Whh2;
    ws[idx] = (c < HH) ? W[j * HH + c] : 0.0f;
  } else if (idx < 154000) {
    int j = idx - 153600; ws[idx] = bih1[j] + bhh1[j];
  } else if (idx < 154400) {
    int j = idx - 154000; ws[idx] = bih2[j] + bhh2[j];
  } else if (idx < 154800) {
    ws[idx] = Wih1[idx - 154400];
  } else if (idx < 154900) {
    ws[idx] = Wlin[idx - 154800];
  } else if (idx == 154900) {
    ws[idx] = blin[0];
  }
}

__device__ __forceinline__ float sigf(float v) {
  return 1.0f / (1.0f + __expf(-v));
}
__device__ __forceinline__ float tanh_fast(float v) {
  float t = __expf(2.0f * v);
  return 1.0f - 2.0f / (t + 1.0f);
}

// dynamic LDS layout (floats):
//   gbp [8 rows][8 slices][408]   26112
//   h1  [8][128] (chunk-swizzled)  1024
//   h2  [8][128]                   1024
//   b1s 400, b2s 400, wis 400, wls 100, xs 8
#define L_GBP  0
#define L_H1   26112
#define L_H2   27136
#define L_B1   28160
#define L_B2   28560
#define L_WI   28960
#define L_WL   29360
#define L_XS   29460
#define L_TOT  29468

// physical float offset of logical h element n (swizzled chunk layout)
__device__ __forceinline__ int hphys(int n) {
  int q = n >> 2;
  return ((q & 3) * 8 + (q >> 2)) * 4 + (n & 3);
}

__global__ __launch_bounds__(1024, 4) void lstm_persist(
    const float* __restrict__ x, const float* __restrict__ ws,
    float* __restrict__ out, int T) {
  extern __shared__ float sm[];
  float* gbp = sm + L_GBP;
  float* h1  = sm + L_H1;
  float* h2  = sm + L_H2;
  float* b1s = sm + L_B1;
  float* b2s = sm + L_B2;
  float* wis = sm + L_WI;
  float* wls = sm + L_WL;
  float* xs  = sm + L_XS;

  const int tid = threadIdx.x;
  const int r0  = blockIdx.x * ROWS;

  // ---- init: zero h (incl. padding chunks), stage small vectors ----
  h1[tid] = 0.0f;
  h2[tid] = 0.0f;
  if (tid < 400) {
    b1s[tid] = ws[153600 + tid];
    b2s[tid] = ws[154000 + tid];
    wis[tid] = ws[154400 + tid];
  }
  if (tid < 100) wls[tid] = ws[154800 + tid];
  if (tid < ROWS) xs[tid] = x[(r0 + tid) * T];
  __syncthreads();

  const int  col = tid >> 3;        // 0..127  gate-col group
  const int  s   = tid & 7;         // 0..7    k-slice
  const bool x4  = (col < 16);      // owns 4th gate-col slot (col+384)

  const float* p1b = ws +            s * 6400 + col * 4;
  const float* p2b = ws + PMAT     + s * 6400 + col * 4;
  const float* p3b = ws + 2 * PMAT + s * 6400 + col * 4;
  const int hbase = s * 4;          // h chunk offset for slice s (i*32 + s*4)

  const bool act = (tid < ROWS * HH);
  const int  er  = tid / HH;
  const int  en  = tid - er * HH;
  float c1 = 0.0f, c2 = 0.0f;

  float a0[8], a1[8], a2[8], a3[8];

#pragma unroll 1
  for (int t = 0; t < T; ++t) {
    // ================= layer-1 matvec: W_hh1 @ h1 =================
#pragma unroll
    for (int r = 0; r < 8; ++r) { a0[r] = a1[r] = a2[r] = a3[r] = 0.0f; }
#pragma unroll
    for (int i = 0; i < 4; ++i) {
      const float* pb = p1b + i * 1600;
      float4 w0 = *(const float4*)pb;
      float4 w1 = *(const float4*)(pb + 512);
      float4 w2 = *(const float4*)(pb + 1024);
      const int ho = i * 32 + hbase;
#pragma unroll
      for (int r = 0; r < 8; ++r) {
        float4 h = *(const float4*)&h1[r * 128 + ho];
        a0[r] = fmaf(w0.x, h.x, fmaf(w0.y, h.y, fmaf(w0.z, h.z, fmaf(w0.w, h.w, a0[r]))));
        a1[r] = fmaf(w1.x, h.x, fmaf(w1.y, h.y, fmaf(w1.z, h.z, fmaf(w1.w, h.w, a1[r]))));
        a2[r] = fmaf(w2.x, h.x, fmaf(w2.y, h.y, fmaf(w2.z, h.z, fmaf(w2.w, h.w, a2[r]))));
      }
      if (x4) {
        float4 w3 = *(const float4*)(pb + 1536);
#pragma unroll
        for (int r = 0; r < 8; ++r) {
          float4 h = *(const float4*)&h1[r * 128 + ho];
          a3[r] = fmaf(w3.x, h.x, fmaf(w3.y, h.y, fmaf(w3.z, h.z, fmaf(w3.w, h.w, a3[r]))));
        }
      }
    }
#pragma unroll
    for (int r = 0; r < 8; ++r) {
      float* g = &gbp[(r * 8 + s) * 408];
      g[col]       = a0[r];
      g[col + 128] = a1[r];
      g[col + 256] = a2[r];
      if (x4) g[col + 384] = a3[r];
    }
    __syncthreads();

    // ================= layer-1 activations =================
    if (act) {
      float xv = xs[er];
      float gs[4];
#pragma unroll
      for (int g = 0; g < 4; ++g) {
        int j = en + g * HH;
        float v = 0.0f;
#pragma unroll
        for (int ss = 0; ss < 8; ++ss) v += gbp[(er * 8 + ss) * 408 + j];
        gs[g] = v + b1s[j] + wis[j] * xv;
      }
      float iv = sigf(gs[0]), fv = sigf(gs[1]);
      float gv = tanh_fast(gs[2]), ov = sigf(gs[3]);
      c1 = fv * c1 + iv * gv;
      h1[er * 128 + hphys(en)] = ov * tanh_fast(c1);
    }
    __syncthreads();

    // ================= layer-2 matvec: W_ih2 @ h1 + W_hh2 @ h2 =================
#pragma unroll
    for (int r = 0; r < 8; ++r) { a0[r] = a1[r] = a2[r] = a3[r] = 0.0f; }
#pragma unroll
    for (int i = 0; i < 4; ++i) {
      const int ho = i * 32 + hbase;
      {
        const float* pb = p2b + i * 1600;
        float4 w0 = *(const float4*)pb;
        float4 w1 = *(const float4*)(pb + 512);
        float4 w2 = *(const float4*)(pb + 1024);
#pragma unroll
        for (int r = 0; r < 8; ++r) {
          float4 h = *(const float4*)&h1[r * 128 + ho];
          a0[r] = fmaf(w0.x, h.x, fmaf(w0.y, h.y, fmaf(w0.z, h.z, fmaf(w0.w, h.w, a0[r]))));
          a1[r] = fmaf(w1.x, h.x, fmaf(w1.y, h.y, fmaf(w1.z, h.z, fmaf(w1.w, h.w, a1[r]))));
          a2[r] = fmaf(w2.x, h.x, fmaf(w2.y, h.y, fmaf(w2.z, h.z, fmaf(w2.w, h.w, a2[r]))));
        }
        if (x4) {
          float4 w3 = *(const float4*)(pb + 1536);
#pragma unroll
          for (int r = 0; r < 8; ++r) {
            float4 h = *(const float4*)&h1[r * 128 + ho];
            a3[r] = fmaf(w3.x, h.x, fmaf(w3.y, h.y, fmaf(w3.z, h.z, fmaf(w3.w, h.w, a3[r]))));
          }
        }
      }
      {
        const float* pb = p3b + i * 1600;
        float4 w0 = *(const float4*)pb;
        float4 w1 = *(const float4*)(pb + 512);
        float4 w2 = *(const float4*)(pb + 1024);
#pragma unroll
        for (int r = 0; r < 8; ++r) {
          float4 h = *(const float4*)&h2[r * 128 + ho];
          a0[r] = fmaf(w0.x, h.x, fmaf(w0.y, h.y, fmaf(w0.z, h.z, fmaf(w0.w, h.w, a0[r]))));
          a1[r] = fmaf(w1.x, h.x, fmaf(w1.y, h.y, fmaf(w1.z, h.z, fmaf(w1.w, h.w, a1[r]))));
          a2[r] = fmaf(w2.x, h.x, fmaf(w2.y, h.y, fmaf(w2.z, h.z, fmaf(w2.w, h.w, a2[r]))));
        }
        if (x4) {
          float4 w3 = *(const float4*)(pb + 1536);
#pragma unroll
          for (int r = 0; r < 8; ++r) {
            float4 h = *(const float4*)&h2[r * 128 + ho];
            a3[r] = fmaf(w3.x, h.x, fmaf(w3.y, h.y, fmaf(w3.z, h.z, fmaf(w3.w, h.w, a3[r]))));
          }
        }
      }
    }
#pragma unroll
    for (int r = 0; r < 8; ++r) {
      float* g = &gbp[(r * 8 + s) * 408];
      g[col]       = a0[r];
      g[col + 128] = a1[r];
      g[col + 256] = a2[r];
      if (x4) g[col + 384] = a3[r];
    }
    __syncthreads();

    // ================= layer-2 activations + x prefetch =================
    if (act) {
      float gs[4];
#pragma unroll
      for (int g = 0; g < 4; ++g) {
        int j = en + g * HH;
        float v = 0.0f;
#pragma unroll
        for (int ss = 0; ss < 8; ++ss) v += gbp[(er * 8 + ss) * 408 + j];
        gs[g] = v + b2s[j];
      }
      float iv = sigf(gs[0]), fv = sigf(gs[1]);
      float gv = tanh_fast(gs[2]), ov = sigf(gs[3]);
      c2 = fv * c2 + iv * gv;
      h2[er * 128 + hphys(en)] = ov * tanh_fast(c2);
    }
    if (tid < ROWS && (t + 1) < T) xs[tid] = x[(r0 + tid) * T + t + 1];
    __syncthreads();
  }

  // ================= output: out[r] = h2[r]·wlin + blin =================
  if (tid < 256) {
    int rr = tid >> 5;
    int lk = tid & 31;
    float p = 0.0f;
#pragma unroll
    for (int n0 = 0; n0 < 4; ++n0) {
      int n = lk + 32 * n0;
      if (n < HH) p += h2[rr * 128 + hphys(n)] * wls[n];
    }
#pragma unroll
    for (int sh = 16; sh > 0; sh >>= 1) p += __shfl_down(p, sh, 32);
    if (lk == 0) out[r0 + rr] = p + ws[154900];
  }
}

// ---------------- launcher ----------------
extern "C" void kernel_launch(void* const* d_in, const int* in_sizes, int n_in,
                              void* d_out, int out_size, void* d_ws, size_t ws_size,
                              hipStream_t stream) {
  const float* x    = (const float*)d_in[0];
  const float* Wih1 = (const float*)d_in[1];
  const float* Whh1 = (const float*)d_in[2];
  const float* bih1 = (const float*)d_in[3];
  const float* bhh1 = (const float*)d_in[4];
  const float* Wih2 = (const float*)d_in[5];
  const float* Whh2 = (const float*)d_in[6];
  const float* bih2 = (const float*)d_in[7];
  const float* bhh2 = (const float*)d_in[8];
  const float* Wlin = (const float*)d_in[9];
  const float* blin = (const float*)d_in[10];

  float* ws  = (float*)d_ws;
  float* out = (float*)d_out;

  const int B = in_sizes[0] / T_STEPS;   // 2048

  pack_kernel<<<(WS_TOTAL + 1023) / 1024, 1024, 0, stream>>>(
      Whh1, Wih2, Whh2, bih1, bhh1, bih2, bhh2, Wih1, Wlin, blin, ws);

  lstm_persist<<<B / ROWS, 1024, L_TOT * 4, stream>>>(x, ws, out, T_STEPS);
}

// Round 3
// 2695.615 us; speedup vs baseline: 18.5124x; 18.5124x over previous
//
#include <hip/hip_runtime.h>

#define T_STEPS 256
#define HH      100
#define ROWS    8
#define NMV     500    // active matvec threads (100 j-cols x 5 k-slices)
#define BLK     512

// ws float layout:
//   [0      .. 120000)  P packed weights: flat = (((m*4 + c)*5 + i)*500 + t)*4 + kk
//                       = W_m[c*100 + j][s*20 + i*4 + kk]  with t = s*100 + j
//                       m: 0=W_hh1, 1=W_ih2, 2=W_hh2
//   [120000 ..120400)   b1s = b_ih1 + b_hh1
//   [120400 ..120800)   b2s = b_ih2 + b_hh2
//   [120800 ..121200)   wis = W_ih1[:,0]
//   [121200 ..121300)   wls = W_lin[0][:]
//   [121300]            blin
#define WS_TOTAL 121301

__global__ __launch_bounds__(512) void pack_kernel(
    const float* __restrict__ Whh1, const float* __restrict__ Wih2,
    const float* __restrict__ Whh2,
    const float* __restrict__ bih1, const float* __restrict__ bhh1,
    const float* __restrict__ bih2, const float* __restrict__ bhh2,
    const float* __restrict__ Wih1, const float* __restrict__ Wlin,
    const float* __restrict__ blin, float* __restrict__ ws) {
  int idx = blockIdx.x * BLK + threadIdx.x;
  if (idx < 120000) {
    int kk = idx & 3;
    int q  = idx >> 2;          // ((m*4+c)*5+i)*500 + t
    int t  = q % 500;
    int q2 = q / 500;           // (m*4+c)*5 + i
    int i  = q2 % 5;
    int q3 = q2 / 5;            // m*4 + c
    int c  = q3 & 3;
    int m  = q3 >> 2;
    int s  = t / 100;
    int j  = t - s * 100;
    int col = c * 100 + j;      // output row of W (0..399)
    int k   = s * 20 + i * 4 + kk;  // 0..99
    const float* W = (m == 0) ? Whh1 : (m == 1) ? Wih2 : Whh2;
    ws[idx] = W[col * HH + k];
  } else if (idx < 120400) {
    int j = idx - 120000; ws[idx] = bih1[j] + bhh1[j];
  } else if (idx < 120800) {
    int j = idx - 120400; ws[idx] = bih2[j] + bhh2[j];
  } else if (idx < 121200) {
    ws[idx] = Wih1[idx - 120800];
  } else if (idx < 121300) {
    ws[idx] = Wlin[idx - 121200];
  } else if (idx == 121300) {
    ws[idx] = blin[0];
  }
}

__device__ __forceinline__ float sigf(float v) {
  return 1.0f / (1.0f + __expf(-v));
}
__device__ __forceinline__ float tanh_fast(float v) {
  float t = __expf(2.0f * v);
  return 1.0f - 2.0f / (t + 1.0f);
}

// matvec partial: acc[c][r] += sum_k W_m[c*100+j][k] * hb[r][k] over this
// thread's k-slice. wp = ws + tid*4; weight offsets are compile-time.
__device__ __forceinline__ void mv4(const float* __restrict__ wp, int mbase,
                                    const float (*__restrict__ hb)[HH],
                                    int s20, float acc[4][8]) {
#pragma unroll
  for (int i = 0; i < 5; ++i) {
    float4 w0 = *(const float4*)(wp + (mbase +  0 + i) * 2000);
    float4 w1 = *(const float4*)(wp + (mbase +  5 + i) * 2000);
    float4 w2 = *(const float4*)(wp + (mbase + 10 + i) * 2000);
    float4 w3 = *(const float4*)(wp + (mbase + 15 + i) * 2000);
#pragma unroll
    for (int r = 0; r < 8; ++r) {
      float4 h = *(const float4*)&hb[r][s20 + i * 4];
      acc[0][r] = fmaf(w0.x, h.x, fmaf(w0.y, h.y, fmaf(w0.z, h.z, fmaf(w0.w, h.w, acc[0][r]))));
      acc[1][r] = fmaf(w1.x, h.x, fmaf(w1.y, h.y, fmaf(w1.z, h.z, fmaf(w1.w, h.w, acc[1][r]))));
      acc[2][r] = fmaf(w2.x, h.x, fmaf(w2.y, h.y, fmaf(w2.z, h.z, fmaf(w2.w, h.w, acc[2][r]))));
      acc[3][r] = fmaf(w3.x, h.x, fmaf(w3.y, h.y, fmaf(w3.z, h.z, fmaf(w3.w, h.w, acc[3][r]))));
    }
  }
}

__global__ __launch_bounds__(512) void lstm_persist(
    const float* __restrict__ x, const float* __restrict__ ws,
    float* __restrict__ out, int T) {
  __shared__ float gbp[5][ROWS][400];
  __shared__ __align__(16) float h1[ROWS][HH];
  __shared__ __align__(16) float h2[ROWS][HH];
  __shared__ float b1s[400], b2s[400], wis[400], wls[HH], xs[ROWS];

  const int tid = threadIdx.x;
  const int r0  = blockIdx.x * ROWS;

  // ---- init ----
  if (tid < 400) {
    b1s[tid] = ws[120000 + tid];
    b2s[tid] = ws[120400 + tid];
    wis[tid] = ws[120800 + tid];
  }
  if (tid < HH) wls[tid] = ws[121200 + tid];
#pragma unroll
  for (int p = 0; p < 2; ++p) {
    int e = tid + 512 * p;
    if (e < ROWS * HH) { (&h1[0][0])[e] = 0.0f; (&h2[0][0])[e] = 0.0f; }
  }
  if (tid < ROWS) xs[tid] = x[(r0 + tid) * T];
  __syncthreads();

  const bool mv  = (tid < NMV);
  const int  s   = tid / 100;          // k-slice 0..4
  const int  j   = tid - s * 100;      // col base 0..99
  const int  s20 = s * 20;
  const float* wp = ws + tid * 4;

  // act-phase element assignment: pass0 -> e=tid, pass1 -> e=tid+512 (tid<288)
  const int e0r = tid / 100, e0n = tid - e0r * 100;                    // e<512<800 always ok
  const int e1  = tid + 512;
  const int e1r = e1 / 100, e1n = e1 - e1r * 100;
  const bool a1 = (e1 < ROWS * HH);
  float c1a = 0.f, c1b = 0.f, c2a = 0.f, c2b = 0.f;

#pragma unroll 1
  for (int t = 0; t < T; ++t) {
    // ============ layer-1 matvec: W_hh1 @ h1 ============
    if (mv) {
      float acc[4][8];
#pragma unroll
      for (int c = 0; c < 4; ++c)
#pragma unroll
        for (int r = 0; r < 8; ++r) acc[c][r] = 0.0f;
      mv4(wp, 0, h1, s20, acc);
#pragma unroll
      for (int c = 0; c < 4; ++c)
#pragma unroll
        for (int r = 0; r < 8; ++r) gbp[s][r][c * 100 + j] = acc[c][r];
    }
    __syncthreads();

    // ============ layer-1 activations ============
    {
      // pass 0
      {
        float xv = xs[e0r];
        float g[4];
#pragma unroll
        for (int gg = 0; gg < 4; ++gg) {
          int jj = e0n + 100 * gg;
          float v = gbp[0][e0r][jj] + gbp[1][e0r][jj] + gbp[2][e0r][jj] +
                    gbp[3][e0r][jj] + gbp[4][e0r][jj];
          g[gg] = v + b1s[jj] + wis[jj] * xv;
        }
        float iv = sigf(g[0]), fv = sigf(g[1]);
        float gv = tanh_fast(g[2]), ov = sigf(g[3]);
        c1a = fv * c1a + iv * gv;
        h1[e0r][e0n] = ov * tanh_fast(c1a);
      }
      // pass 1
      if (a1) {
        float xv = xs[e1r];
        float g[4];
#pragma unroll
        for (int gg = 0; gg < 4; ++gg) {
          int jj = e1n + 100 * gg;
          float v = gbp[0][e1r][jj] + gbp[1][e1r][jj] + gbp[2][e1r][jj] +
                    gbp[3][e1r][jj] + gbp[4][e1r][jj];
          g[gg] = v + b1s[jj] + wis[jj] * xv;
        }
        float iv = sigf(g[0]), fv = sigf(g[1]);
        float gv = tanh_fast(g[2]), ov = sigf(g[3]);
        c1b = fv * c1b + iv * gv;
        h1[e1r][e1n] = ov * tanh_fast(c1b);
      }
    }
    __syncthreads();

    // ============ layer-2 matvec: W_ih2 @ h1 + W_hh2 @ h2 ============
    if (mv) {
      float acc[4][8];
#pragma unroll
      for (int c = 0; c < 4; ++c)
#pragma unroll
        for (int r = 0; r < 8; ++r) acc[c][r] = 0.0f;
      mv4(wp, 20, h1, s20, acc);
      mv4(wp, 40, h2, s20, acc);
#pragma unroll
      for (int c = 0; c < 4; ++c)
#pragma unroll
        for (int r = 0; r < 8; ++r) gbp[s][r][c * 100 + j] = acc[c][r];
    }
    __syncthreads();

    // ============ layer-2 activations + x prefetch ============
    {
      {
        float g[4];
#pragma unroll
        for (int gg = 0; gg < 4; ++gg) {
          int jj = e0n + 100 * gg;
          float v = gbp[0][e0r][jj] + gbp[1][e0r][jj] + gbp[2][e0r][jj] +
                    gbp[3][e0r][jj] + gbp[4][e0r][jj];
          g[gg] = v + b2s[jj];
        }
        float iv = sigf(g[0]), fv = sigf(g[1]);
        float gv = tanh_fast(g[2]), ov = sigf(g[3]);
        c2a = fv * c2a + iv * gv;
        h2[e0r][e0n] = ov * tanh_fast(c2a);
      }
      if (a1) {
        float g[4];
#pragma unroll
        for (int gg = 0; gg < 4; ++gg) {
          int jj = e1n + 100 * gg;
          float v = gbp[0][e1r][jj] + gbp[1][e1r][jj] + gbp[2][e1r][jj] +
                    gbp[3][e1r][jj] + gbp[4][e1r][jj];
          g[gg] = v + b2s[jj];
        }
        float iv = sigf(g[0]), fv = sigf(g[1]);
        float gv = tanh_fast(g[2]), ov = sigf(g[3]);
        c2b = fv * c2b + iv * gv;
        h2[e1r][e1n] = ov * tanh_fast(c2b);
      }
    }
    if (tid < ROWS && (t + 1) < T) xs[tid] = x[(r0 + tid) * T + t + 1];
    __syncthreads();
  }

  // ============ output: out[r] = h2[r]·wlin + blin ============
  {
    int row  = tid >> 6;   // 0..7 (8 waves)
    int lane = tid & 63;
    float p = h2[row][lane] * wls[lane];
    if (lane + 64 < HH) p += h2[row][lane + 64] * wls[lane + 64];
#pragma unroll
    for (int off = 32; off > 0; off >>= 1) p += __shfl_down(p, off, 64);
    if (lane == 0) out[r0 + row] = p + ws[121300];
  }
}

// ---------------- launcher ----------------
extern "C" void kernel_launch(void* const* d_in, const int* in_sizes, int n_in,
                              void* d_out, int out_size, void* d_ws, size_t ws_size,
                              hipStream_t stream) {
  const float* x    = (const float*)d_in[0];
  const float* Wih1 = (const float*)d_in[1];
  const float* Whh1 = (const float*)d_in[2];
  const float* bih1 = (const float*)d_in[3];
  const float* bhh1 = (const float*)d_in[4];
  const float* Wih2 = (const float*)d_in[5];
  const float* Whh2 = (const float*)d_in[6];
  const float* bih2 = (const float*)d_in[7];
  const float* bhh2 = (const float*)d_in[8];
  const float* Wlin = (const float*)d_in[9];
  const float* blin = (const float*)d_in[10];

  float* ws  = (float*)d_ws;
  float* out = (float*)d_out;

  const int B = in_sizes[0] / T_STEPS;   // 2048

  pack_kernel<<<(WS_TOTAL + BLK - 1) / BLK, BLK, 0, stream>>>(
      Whh1, Wih2, Whh2, bih1, bhh1, bih2, bhh2, Wih1, Wlin, blin, ws);

  lstm_persist<<<B / ROWS, BLK, 0, stream>>>(x, ws, out, T_STEPS);
}